// Round 4
// baseline (1533.655 us; speedup 1.0000x reference)
//
#include <hip/hip_runtime.h>

#define NTAGS  256
#define TLEN   512
#define BATCH  256
#define NEGINF (-3.0e38f)

// One workgroup (1024 threads) per batch. Thread (c, h): c = output tag
// column (tid & 255), h = prev-quarter (tid >> 8). trans[64h+p][c] register-
// resident (VGPR/AGPR). Alpha broadcast: ONE per-lane ds_read_b32 per step,
// then 64x v_readlane -> SGPR, consumed as scalar operand of v_add_f32 —
// removes the 16x wave-uniform ds_read_b128 that was saturating the LDS pipe.
__global__ __launch_bounds__(1024, 4)
void viterbi_dp(const float* __restrict__ emis,   // [B][T][N]
                const float* __restrict__ mask,   // [B][T]
                const float* __restrict__ trans,  // [N][N]
                float* __restrict__ out)          // [B] scores ++ [B][T] paths (float)
{
    __shared__ __align__(16) float  alphaBuf[NTAGS];
    __shared__ __align__(16) float2 pv[3][NTAGS];          // partials of h=1..3
    __shared__ unsigned char bptL[(TLEN - 1) * NTAGS];     // 130816 B
    __shared__ float endScore[NTAGS];

    const int tid   = threadIdx.x;
    const int c     = tid & (NTAGS - 1);
    const int h     = tid >> 8;            // wave-uniform
    const int lane  = tid & 63;
    const int b     = blockIdx.x;
    const int pbase = h * 64;

    // 64 transition values trans[pbase+p][c], loaded once. Per-element opaque
    // pin blocks rematerialization inside the t-loop (round-2 lesson); the
    // compiler may home them in AGPRs — direct AGPR sources are fine.
    float treg[64];
#pragma unroll
    for (int p = 0; p < 64; ++p) {
        treg[p] = trans[(pbase + p) * NTAGS + c];
        asm volatile("" : "+v"(treg[p]));
    }

    const float* eb = emis + (size_t)b * TLEN * NTAGS;
    const float* mb = mask + (size_t)b * TLEN;

    // alphas0 = trans[SOS=0][c] + em[b][0][c]
    if (h == 0) alphaBuf[c] = trans[c] + eb[c];
    __syncthreads();

    // software-pipeline emissions/mask one step ahead
    float emCur = eb[NTAGS + c];
    float mCur  = mb[1];

    for (int t = 1; t < TLEN; ++t) {
        float emNext = 0.0f, mNext = 1.0f;
        if (t + 1 < TLEN) {
            emNext = eb[(t + 1) * NTAGS + c];
            mNext  = mb[t + 1];
        }

        // One conflict-free per-lane read of my quarter's alphas.
        const int avi = __float_as_int(alphaBuf[pbase + lane]);

        // partial max/argmax over my 64 prevs, ascending, strict > (first max),
        // rounding exactly as reference: (alpha[p] + trans[p][c]) + em[c].
        // alpha[p] arrives via readlane -> SGPR (no LDS traffic).
        float gb = NEGINF;
        int   ga = 0;
#pragma unroll
        for (int q = 0; q < 16; ++q) {
            const float a0 = __int_as_float(__builtin_amdgcn_readlane(avi, 4 * q + 0));
            const float a1 = __int_as_float(__builtin_amdgcn_readlane(avi, 4 * q + 1));
            const float a2 = __int_as_float(__builtin_amdgcn_readlane(avi, 4 * q + 2));
            const float a3 = __int_as_float(__builtin_amdgcn_readlane(avi, 4 * q + 3));
            float s;
            s = (a0 + treg[4 * q + 0]) + emCur; if (s > gb) { gb = s; ga = 4 * q + 0; }
            s = (a1 + treg[4 * q + 1]) + emCur; if (s > gb) { gb = s; ga = 4 * q + 1; }
            s = (a2 + treg[4 * q + 2]) + emCur; if (s > gb) { gb = s; ga = 4 * q + 2; }
            s = (a3 + treg[4 * q + 3]) + emCur; if (s > gb) { gb = s; ga = 4 * q + 3; }
        }

        if (h) pv[h - 1][c] = make_float2(gb, __int_as_float(ga + pbase));
        __syncthreads();

        // combine across h (h==0 waves only), h ascending, strict > keeps
        // the global FIRST argmax.
        if (h == 0) {
            const float2 P1 = pv[0][c];
            const float2 P2 = pv[1][c];
            const float2 P3 = pv[2][c];
            float best = gb; int arg = ga;
            if (P1.x > best) { best = P1.x; arg = __float_as_int(P1.y); }
            if (P2.x > best) { best = P2.x; arg = __float_as_int(P2.y); }
            if (P3.x > best) { best = P3.x; arg = __float_as_int(P3.y); }
            const float aOld = alphaBuf[c];
            alphaBuf[c] = mCur * best + (1.0f - mCur) * aOld;
            bptL[(t - 1) * NTAGS + c] = (unsigned char)arg;
        }
        emCur = emNext;
        mCur  = mNext;
        __syncthreads();
    }

    // end_scores = alpha + trans[:, EOS=1]
    if (h == 0) endScore[c] = alphaBuf[c] + trans[c * NTAGS + 1];
    __syncthreads();

    if (tid == 0) {
        float best = endScore[0]; int arg = 0;
        for (int i = 1; i < NTAGS; ++i) {
            float v = endScore[i];
            if (v > best) { best = v; arg = i; }
        }
        out[b] = best;

        // backtrace entirely from LDS
        float* pout = out + BATCH + (size_t)b * TLEN;
        int tag = arg;
        pout[TLEN - 1] = (float)tag;
        for (int t = TLEN - 2; t >= 0; --t) {
            tag = bptL[t * NTAGS + tag];
            pout[t] = (float)tag;
        }
    }
}

extern "C" void kernel_launch(void* const* d_in, const int* in_sizes, int n_in,
                              void* d_out, int out_size, void* d_ws, size_t ws_size,
                              hipStream_t stream) {
    (void)d_ws; (void)ws_size; (void)in_sizes; (void)n_in; (void)out_size;
    const float* emis  = (const float*)d_in[0];
    const float* mask  = (const float*)d_in[1];
    const float* trans = (const float*)d_in[2];
    float* out = (float*)d_out;

    viterbi_dp<<<dim3(BATCH), dim3(1024), 0, stream>>>(emis, mask, trans, out);
}

// Round 5
// 1185.981 us; speedup vs baseline: 1.2932x; 1.2932x over previous
//
#include <hip/hip_runtime.h>

#define NTAGS  256
#define TLEN   512
#define BATCH  256
#define QS     68            // padded quarter stride (floats): 4 lane-groups hit disjoint banks
#define NEGINF (-3.0e38f)

// One workgroup (1024 threads) per batch. Wave w owns columns 16w..16w+15;
// lane l: c = 16w + (l&15), quarter h = l>>4 scans prevs [64h, 64h+64).
// Cross-quarter argmax combine = 2-stage shfl_xor butterfly in-register
// (first-index tie-break) -> ONE barrier per step, no LDS combine phase.
// trans column in 64 regs/thread; alpha ping-pong in padded LDS; bpt in LDS.
__global__ __launch_bounds__(1024, 4)
void viterbi_dp(const float* __restrict__ emis,   // [B][T][N]
                const float* __restrict__ mask,   // [B][T]
                const float* __restrict__ trans,  // [N][N]
                float* __restrict__ out)          // [B] scores ++ [B][T] paths (float)
{
    __shared__ __align__(16) float aSh[2][4 * QS];         // padded alpha, ping-pong
    __shared__ unsigned char bptL[(TLEN - 1) * NTAGS];     // 130816 B
    __shared__ float endS[NTAGS];

    const int tid   = threadIdx.x;
    const int w     = tid >> 6;
    const int lane  = tid & 63;
    const int c     = (w << 4) | (lane & 15);
    const int h     = lane >> 4;
    const int pbase = h << 6;
    const int b     = blockIdx.x;

    // 64 transition values trans[pbase+p][c], loaded once, register-resident.
    float treg[64];
#pragma unroll
    for (int p = 0; p < 64; ++p) {
        treg[p] = trans[(pbase + p) * NTAGS + c];
        asm volatile("" : "+v"(treg[p]));
    }

    const float* eb = emis + (size_t)b * TLEN * NTAGS;
    const float* mb = mask + (size_t)b * TLEN;

    // alphas0[c] = trans[SOS=0][c] + em[b][0][c]; register-carried aOld,
    // one padded copy in LDS buf0 (written by lane-group 0).
    float aOld = trans[c] + eb[c];
    if (h == 0) aSh[0][QS * (c >> 6) + (c & 63)] = aOld;
    __syncthreads();

    float emCur = eb[NTAGS + c];
    float mCur  = mb[1];

    int cur = 0;
    for (int t = 1; t < TLEN; ++t) {
        float emNext = 0.0f, mNext = 1.0f;
        if (t + 1 < TLEN) {
            emNext = eb[(t + 1) * NTAGS + c];
            mNext  = mb[t + 1];
        }

        // scan my quarter: ascending p, strict > keeps FIRST max; rounding
        // exactly as reference: (alpha[p] + trans[p][c]) + em[c]
        const float4* a4 = (const float4*)(&aSh[cur][h * QS]);
        float gb = NEGINF;
        int   ga = 0;
#pragma unroll
        for (int q = 0; q < 16; ++q) {
            const float4 al = a4[q];
            float s;
            s = (al.x + treg[4 * q + 0]) + emCur; if (s > gb) { gb = s; ga = 4 * q + 0; }
            s = (al.y + treg[4 * q + 1]) + emCur; if (s > gb) { gb = s; ga = 4 * q + 1; }
            s = (al.z + treg[4 * q + 2]) + emCur; if (s > gb) { gb = s; ga = 4 * q + 2; }
            s = (al.w + treg[4 * q + 3]) + emCur; if (s > gb) { gb = s; ga = 4 * q + 3; }
        }
        ga += pbase;

        // butterfly combine across the 4 quarters (lanes xor 16, xor 32).
        // take partner iff strictly larger, or equal with smaller index
        // (= global FIRST argmax).
#pragma unroll
        for (int m = 16; m <= 32; m <<= 1) {
            const float pvv = __shfl_xor(gb, m, 64);
            const int   paa = __shfl_xor(ga, m, 64);
            const bool take = (pvv > gb) || ((pvv == gb) && (paa < ga));
            gb = take ? pvv : gb;
            ga = take ? paa : ga;
        }

        // masked blend exactly as reference: m*max + (1-m)*alpha
        const float aNew = mCur * gb + (1.0f - mCur) * aOld;
        if (h == 0)      aSh[cur ^ 1][QS * (c >> 6) + (c & 63)] = aNew;
        else if (h == 1) bptL[(t - 1) * NTAGS + c] = (unsigned char)ga;

        aOld  = aNew;
        emCur = emNext;
        mCur  = mNext;
        cur  ^= 1;
        __syncthreads();
    }

    // end_scores = alpha + trans[:, EOS=1]
    if (h == 0) endS[c] = aOld + trans[c * NTAGS + 1];
    __syncthreads();

    if (tid == 0) {
        float best = endS[0]; int arg = 0;
        for (int i = 1; i < NTAGS; ++i) {
            float v = endS[i];
            if (v > best) { best = v; arg = i; }
        }
        out[b] = best;

        // backtrace entirely from LDS
        float* pout = out + BATCH + (size_t)b * TLEN;
        int tag = arg;
        pout[TLEN - 1] = (float)tag;
        for (int t = TLEN - 2; t >= 0; --t) {
            tag = bptL[t * NTAGS + tag];
            pout[t] = (float)tag;
        }
    }
}

extern "C" void kernel_launch(void* const* d_in, const int* in_sizes, int n_in,
                              void* d_out, int out_size, void* d_ws, size_t ws_size,
                              hipStream_t stream) {
    (void)d_ws; (void)ws_size; (void)in_sizes; (void)n_in; (void)out_size;
    const float* emis  = (const float*)d_in[0];
    const float* mask  = (const float*)d_in[1];
    const float* trans = (const float*)d_in[2];
    float* out = (float*)d_out;

    viterbi_dp<<<dim3(BATCH), dim3(1024), 0, stream>>>(emis, mask, trans, out);
}